// Round 1
// baseline (361.884 us; speedup 1.0000x reference)
//
#include <hip/hip_runtime.h>

#define D 64
#define CHARSET 128
#define NREL 22
#define GAMMA 1.0f

__global__ void init_out(float* out, float v) {
    if (threadIdx.x == 0 && blockIdx.x == 0) out[0] = v;
}

__global__ __launch_bounds__(256) void attr_loss_kernel(
    const int* __restrict__ char_ids,
    const int* __restrict__ seg_ids,
    const int* __restrict__ head_ids,
    const int* __restrict__ rel_ids,
    const float* __restrict__ char_emb,
    const float* __restrict__ rel_emb,
    const float* __restrict__ ent_emb,
    float* __restrict__ out,
    int n_triples, int total_chars, int triples_per_wave)
{
    __shared__ float lds_emb[CHARSET * D];   // 32 KB char embedding table
    __shared__ float lds_rel[NREL * D];      // 5.5 KB relation table
    __shared__ float red[4];

    for (int i = threadIdx.x; i < CHARSET * D; i += 256) lds_emb[i] = char_emb[i];
    for (int i = threadIdx.x; i < NREL * D; i += 256)    lds_rel[i] = rel_emb[i];
    __syncthreads();

    const int wib  = threadIdx.x >> 6;      // wave index in block (0..3)
    const int lane = threadIdx.x & 63;      // = dimension d
    const int gwave = blockIdx.x * 4 + wib;

    const int s0 = gwave * triples_per_wave;
    const int s1 = min(s0 + triples_per_wave, n_triples);
    float acc = 0.f;

    if (s0 < n_triples) {
        // binary search: first char index with seg_ids[i] >= s0
        int lo = 0, hi = total_chars;
        while (lo < hi) {
            int mid = (lo + hi) >> 1;
            if (seg_ids[mid] < s0) lo = mid + 1; else hi = mid;
        }
        int c = __builtin_amdgcn_readfirstlane(lo);   // wave-uniform walker

        for (int s = s0; s < s1; ++s) {
            float t = 0.f;
            // walk this segment's contiguous char run
            while (c < total_chars && seg_ids[c] == s) {
                int cid = char_ids[c];
                t += lds_emb[cid * D + lane];
                ++c;
            }
            float h = ent_emb[(long)head_ids[s] * D + lane];  // coalesced 256B row
            float r = lds_rel[rel_ids[s] * D + lane];
            acc += fabsf(h + r - t);
            // note: max(dist+GAMMA,0) == dist+GAMMA since dist>=0; GAMMA term
            // is added once as N*GAMMA in init_out.
        }
    }

    // 64-lane wave reduction
    #pragma unroll
    for (int off = 32; off > 0; off >>= 1)
        acc += __shfl_down(acc, off, 64);
    if (lane == 0) red[wib] = acc;
    __syncthreads();
    if (threadIdx.x == 0)
        atomicAdd(out, red[0] + red[1] + red[2] + red[3]);
}

extern "C" void kernel_launch(void* const* d_in, const int* in_sizes, int n_in,
                              void* d_out, int out_size, void* d_ws, size_t ws_size,
                              hipStream_t stream) {
    const int*   char_ids = (const int*)  d_in[0];
    const int*   seg_ids  = (const int*)  d_in[1];
    const int*   head_ids = (const int*)  d_in[2];
    const int*   rel_ids  = (const int*)  d_in[3];
    const float* char_emb = (const float*)d_in[4];
    const float* rel_emb  = (const float*)d_in[5];
    const float* ent_emb  = (const float*)d_in[6];
    float* out = (float*)d_out;

    const int total_chars = in_sizes[0];
    const int n_triples   = in_sizes[2];

    const int blocks = 1024;                 // 4096 waves
    const int waves  = blocks * 4;
    const int tpw    = (n_triples + waves - 1) / waves;   // 25

    init_out<<<1, 64, 0, stream>>>(out, (float)n_triples * GAMMA);
    attr_loss_kernel<<<blocks, 256, 0, stream>>>(
        char_ids, seg_ids, head_ids, rel_ids,
        char_emb, rel_emb, ent_emb, out,
        n_triples, total_chars, tpw);
}

// Round 2
// 196.116 us; speedup vs baseline: 1.8453x; 1.8453x over previous
//
#include <hip/hip_runtime.h>

#define D 64
#define CHARSET 128
#define NREL 22
#define GAMMA 1.0f
#define TPW 12      // triples (segments) per wave
#define WPB 4       // waves per block

__global__ void init_out(float* out, float v) {
    if (threadIdx.x == 0 && blockIdx.x == 0) out[0] = v;
}

// cooperative 64-ary lower_bound: first i in [0,total) with seg[i] >= target
__device__ __forceinline__ int lower_bound64(const int* __restrict__ seg,
                                             int total, int target, int lane) {
    int lo = 0, hi = total;
    while (hi - lo > 64) {
        int step = (hi - lo) >> 6;            // >= 1
        int idx = lo + lane * step;           // all < hi since 64*step <= hi-lo
        int v = seg[idx];
        unsigned long long mask = __ballot(v < target);
        if (mask == 0ull) { hi = lo; break; } // seg[lo] >= target already
        int k = 63 - __clzll(mask);           // highest lane with v < target
        int nlo = lo + k * step;
        int nhi = (k == 63) ? hi : (lo + (k + 1) * step);
        lo = nlo; hi = nhi;
    }
    if (hi > lo) {
        int idx = lo + lane;
        int v = (idx < hi) ? seg[idx] : 0x7FFFFFFF;
        unsigned long long lt = __ballot(v < target);
        lo += __popcll(lt);
    }
    return lo;
}

__global__ __launch_bounds__(256) void attr_loss_kernel(
    const int* __restrict__ char_ids,
    const int* __restrict__ seg_ids,
    const int* __restrict__ head_ids,
    const int* __restrict__ rel_ids,
    const float* __restrict__ char_emb,
    const float* __restrict__ rel_emb,
    const float* __restrict__ ent_emb,
    float* __restrict__ out,
    int n_triples, int total_chars)
{
    __shared__ float lds_emb[CHARSET * D];   // 32 KB
    __shared__ float lds_rel[NREL * D];      // 5.5 KB
    __shared__ float lds_u[WPB * TPW * D];   // 12 KB: u = h + r per segment
    __shared__ float red[WPB];

    for (int i = threadIdx.x; i < CHARSET * D; i += 256) lds_emb[i] = char_emb[i];
    for (int i = threadIdx.x; i < NREL * D; i += 256)    lds_rel[i] = rel_emb[i];
    __syncthreads();

    const int wib   = threadIdx.x >> 6;
    const int lane  = threadIdx.x & 63;
    const int gwave = blockIdx.x * WPB + wib;

    const int s0 = gwave * TPW;
    const int s1 = min(s0 + TPW, n_triples);
    float acc = 0.f;

    if (s0 < n_triples) {
        float* uw = &lds_u[wib * TPW * D];

        // ---- precompute u[s] = h[s] + r[s]; unrolled so gathers pipeline ----
        int hid[TPW], rid[TPW];
        #pragma unroll
        for (int i = 0; i < TPW; ++i) {
            int s = s0 + i;
            hid[i] = (s < n_triples) ? head_ids[s] : 0;
            rid[i] = (s < n_triples) ? rel_ids[s]  : 0;
        }
        #pragma unroll
        for (int i = 0; i < TPW; ++i) {
            if (s0 + i < n_triples)
                uw[i * D + lane] =
                    ent_emb[(size_t)hid[i] * D + lane] + lds_rel[rid[i] * D + lane];
        }

        // ---- char range for this wave's segments ----
        int c_begin = lower_bound64(seg_ids, total_chars, s0, lane);
        int c_end   = lower_bound64(seg_ids, total_chars, s1, lane);

        int cur = s0;
        float t = 0.f;

        for (int cb = c_begin; cb < c_end; cb += 64) {
            int c = cb + lane;
            unsigned packed = 0u;
            if (c < c_end)
                packed = ((unsigned)seg_ids[c] << 7) | (unsigned)char_ids[c];
            int m = min(64, c_end - cb);
            for (int j = 0; j < m; ++j) {
                unsigned p = (unsigned)__shfl((int)packed, j, 64);
                int sid = (int)(p >> 7);
                int cid = (int)(p & 127u);
                if (sid != cur) {                       // flush (rare: ~1/40)
                    acc += fabsf(uw[(cur - s0) * D + lane] - t);
                    for (int s = cur + 1; s < sid; ++s) // empty segments
                        acc += fabsf(uw[(s - s0) * D + lane]);
                    cur = sid;
                    t = 0.f;
                }
                t += lds_emb[cid * D + lane];
            }
        }
        // final flush
        acc += fabsf(uw[(cur - s0) * D + lane] - t);
        for (int s = cur + 1; s < s1; ++s)
            acc += fabsf(uw[(s - s0) * D + lane]);
    }

    // wave + block reduction, one atomic per block
    #pragma unroll
    for (int off = 32; off > 0; off >>= 1)
        acc += __shfl_down(acc, off, 64);
    if (lane == 0) red[wib] = acc;
    __syncthreads();
    if (threadIdx.x == 0)
        atomicAdd(out, red[0] + red[1] + red[2] + red[3]);
}

extern "C" void kernel_launch(void* const* d_in, const int* in_sizes, int n_in,
                              void* d_out, int out_size, void* d_ws, size_t ws_size,
                              hipStream_t stream) {
    const int*   char_ids = (const int*)  d_in[0];
    const int*   seg_ids  = (const int*)  d_in[1];
    const int*   head_ids = (const int*)  d_in[2];
    const int*   rel_ids  = (const int*)  d_in[3];
    const float* char_emb = (const float*)d_in[4];
    const float* rel_emb  = (const float*)d_in[5];
    const float* ent_emb  = (const float*)d_in[6];
    float* out = (float*)d_out;

    const int total_chars = in_sizes[0];
    const int n_triples   = in_sizes[2];

    const int per_block = TPW * WPB;                       // 48 triples/block
    const int blocks = (n_triples + per_block - 1) / per_block;

    init_out<<<1, 64, 0, stream>>>(out, (float)n_triples * GAMMA);
    attr_loss_kernel<<<blocks, 256, 0, stream>>>(
        char_ids, seg_ids, head_ids, rel_ids,
        char_emb, rel_emb, ent_emb, out,
        n_triples, total_chars);
}

// Round 3
// 117.800 us; speedup vs baseline: 3.0720x; 1.6648x over previous
//
#include <hip/hip_runtime.h>

#define D 64
#define CHARSET 128
#define GAMMA 1.0f
#define TPW 12      // triples per wave
#define SPG 3       // segments per 16-lane group (TPW = 4*SPG)
#define WPB 4       // waves per block

typedef float f4 __attribute__((ext_vector_type(4)));

__device__ __forceinline__ f4 vabs(f4 v) {
    f4 r; r[0]=__builtin_fabsf(v[0]); r[1]=__builtin_fabsf(v[1]);
    r[2]=__builtin_fabsf(v[2]); r[3]=__builtin_fabsf(v[3]); return r;
}

__global__ void init_out(float* out, float v) {
    if (threadIdx.x == 0 && blockIdx.x == 0) out[0] = v;
}

// cooperative lower_bound in [lo,hi): first i with seg[i] >= target
__device__ __forceinline__ int lower_bound64(const int* __restrict__ seg,
                                             int lo, int hi, int target, int lane) {
    while (hi - lo > 64) {
        int step = (hi - lo) >> 6;
        int idx = lo + lane * step;
        int v = seg[idx];
        unsigned long long mask = __ballot(v < target);
        if (mask == 0ull) { hi = lo; break; }
        int k = 63 - __clzll(mask);
        int nhi = (k == 63) ? hi : (lo + (k + 1) * step);
        lo = lo + k * step; hi = nhi;
    }
    if (hi > lo) {
        int idx = lo + lane;
        int v = (idx < hi) ? seg[idx] : 0x7FFFFFFF;
        lo += __popcll(__ballot(v < target));
    }
    return lo;
}

__global__ __launch_bounds__(256) void attr_loss_kernel(
    const int* __restrict__ char_ids,
    const int* __restrict__ seg_ids,
    const int* __restrict__ head_ids,
    const int* __restrict__ rel_ids,
    const float* __restrict__ char_emb,
    const float* __restrict__ rel_emb,
    const float* __restrict__ ent_emb,
    float* __restrict__ out,
    int n_triples, int total_chars)
{
    __shared__ float lds_emb[CHARSET * D];       // 32 KB
    __shared__ float lds_u[WPB][TPW][D];         // 12 KB: u = h + r
    __shared__ unsigned lds_ids[WPB][64];        // 1 KB id staging (16/group)
    __shared__ float red[WPB];

    // stage char embedding table, vectorized
    for (int i = threadIdx.x; i < CHARSET * D / 4; i += 256)
        ((f4*)lds_emb)[i] = ((const f4*)char_emb)[i];

    const int wib  = threadIdx.x >> 6;
    const int lane = threadIdx.x & 63;
    const int grp  = lane >> 4;          // 0..3: walker group
    const int gl   = lane & 15;          // lane in group -> dims gl*4..+3
    const int gwave = blockIdx.x * WPB + wib;
    const int s0 = gwave * TPW;
    const int s1 = min(s0 + TPW, n_triples);

    // u[i] = h + r into LDS (per-wave private; unrolled so gathers pipeline)
    if (s0 < n_triples) {
        #pragma unroll
        for (int i = 0; i < TPW; ++i) {
            int s = s0 + i;
            if (s < n_triples) {
                int hid = head_ids[s], rid = rel_ids[s];
                lds_u[wib][i][lane] =
                    ent_emb[(size_t)hid * D + lane] + rel_emb[rid * D + lane];
            }
        }
    }
    __syncthreads();

    f4 acc4 = (f4)0.f;

    if (s0 < n_triples) {
        // segment-boundary char positions for the 4 groups
        int b0 = lower_bound64(seg_ids, 0, total_chars, s0, lane);
        int b4 = lower_bound64(seg_ids, b0, total_chars, s1, lane);
        int b1 = lower_bound64(seg_ids, b0, b4, min(s0 + 1 * SPG, s1), lane);
        int b2 = lower_bound64(seg_ids, b1, b4, min(s0 + 2 * SPG, s1), lane);
        int b3 = lower_bound64(seg_ids, b2, b4, min(s0 + 3 * SPG, s1), lane);

        const int b_my  = grp == 0 ? b0 : grp == 1 ? b1 : grp == 2 ? b2 : b3;
        const int ce_my = grp == 0 ? b1 : grp == 1 ? b2 : grp == 2 ? b3 : b4;
        const int sg0   = min(s0 + grp * SPG, s1);
        const int sg1   = min(sg0 + SPG, s1);

        int steps = ce_my - b_my;
        steps = max(steps, __shfl_xor(steps, 16, 64));
        steps = max(steps, __shfl_xor(steps, 32, 64));   // max over groups

        int cur = sg0;
        f4  t4  = (f4)0.f;

        for (int base = 0; base < steps; base += 16) {
            // stage next 16 ids for my group (coalesced 64B runs per group)
            int cidx = b_my + base + gl;
            unsigned pk = 0xFFFFFFFFu;
            if (cidx < ce_my)
                pk = ((unsigned)seg_ids[cidx] << 7) | (unsigned)char_ids[cidx];
            lds_ids[wib][lane] = pk;   // same-wave RAW: compiler inserts lgkmcnt

            #pragma unroll
            for (int k = 0; k < 16; ++k) {
                unsigned p = lds_ids[wib][(lane & 48) + k];  // grp*16 + k
                if (p != 0xFFFFFFFFu) {
                    int sid = (int)(p >> 7);
                    int cid = (int)(p & 127u);
                    if (sid != cur) {                        // flush (~1/40)
                        f4 uv = *(const f4*)&lds_u[wib][cur - s0][gl * 4];
                        acc4 += vabs(uv - t4);
                        for (int s = cur + 1; s < sid; ++s)  // empty segments
                            acc4 += vabs(*(const f4*)&lds_u[wib][s - s0][gl * 4]);
                        cur = sid;
                        t4  = (f4)0.f;
                    }
                    t4 += *(const f4*)&lds_emb[cid * D + gl * 4];
                }
            }
        }

        // final flush for my group
        if (sg1 > sg0) {
            f4 uv = *(const f4*)&lds_u[wib][cur - s0][gl * 4];
            acc4 += vabs(uv - t4);
            for (int s = cur + 1; s < sg1; ++s)
                acc4 += vabs(*(const f4*)&lds_u[wib][s - s0][gl * 4]);
        }
    }

    // reduce: lane -> wave -> block -> one atomic
    float acc = acc4[0] + acc4[1] + acc4[2] + acc4[3];
    #pragma unroll
    for (int off = 32; off > 0; off >>= 1)
        acc += __shfl_down(acc, off, 64);
    if (lane == 0) red[wib] = acc;
    __syncthreads();
    if (threadIdx.x == 0)
        atomicAdd(out, red[0] + red[1] + red[2] + red[3]);
}

extern "C" void kernel_launch(void* const* d_in, const int* in_sizes, int n_in,
                              void* d_out, int out_size, void* d_ws, size_t ws_size,
                              hipStream_t stream) {
    const int*   char_ids = (const int*)  d_in[0];
    const int*   seg_ids  = (const int*)  d_in[1];
    const int*   head_ids = (const int*)  d_in[2];
    const int*   rel_ids  = (const int*)  d_in[3];
    const float* char_emb = (const float*)d_in[4];
    const float* rel_emb  = (const float*)d_in[5];
    const float* ent_emb  = (const float*)d_in[6];
    float* out = (float*)d_out;

    const int total_chars = in_sizes[0];
    const int n_triples   = in_sizes[2];

    const int per_block = TPW * WPB;     // 48 triples/block
    const int blocks = (n_triples + per_block - 1) / per_block;

    init_out<<<1, 64, 0, stream>>>(out, (float)n_triples * GAMMA);
    attr_loss_kernel<<<blocks, 256, 0, stream>>>(
        char_ids, seg_ids, head_ids, rel_ids,
        char_emb, rel_emb, ent_emb, out,
        n_triples, total_chars);
}

// Round 4
// 60.541 us; speedup vs baseline: 5.9775x; 1.9458x over previous
//
#include <hip/hip_runtime.h>

#define D 64
#define CHARSET 128
#define GAMMA 1.0f
#define SPB 64          // segments per block (one per lane)
#define HPAD 132        // padded hist row in words: 16B-aligned, conflict-free

__global__ void init_out(float* out, float v) {
    if (threadIdx.x == 0 && blockIdx.x == 0) out[0] = v;
}

// cooperative lower_bound in [lo,hi): first i with seg[i] >= target
__device__ __forceinline__ int lower_bound64(const int* __restrict__ seg,
                                             int lo, int hi, int target, int lane) {
    while (hi - lo > 64) {
        int step = (hi - lo) >> 6;
        int idx = lo + lane * step;
        int v = seg[idx];
        unsigned long long mask = __ballot(v < target);
        if (mask == 0ull) { hi = lo; break; }
        int k = 63 - __clzll(mask);
        int nhi = (k == 63) ? hi : (lo + (k + 1) * step);
        lo = lo + k * step; hi = nhi;
    }
    if (hi > lo) {
        int idx = lo + lane;
        int v = (idx < hi) ? seg[idx] : 0x7FFFFFFF;
        lo += __popcll(__ballot(v < target));
    }
    return lo;
}

__global__ __launch_bounds__(256) void attr_loss_kernel(
    const int* __restrict__ char_ids,
    const int* __restrict__ seg_ids,
    const int* __restrict__ head_ids,
    const int* __restrict__ rel_ids,
    const float* __restrict__ char_emb,
    const float* __restrict__ rel_emb,
    const float* __restrict__ ent_emb,
    float* __restrict__ out,
    int n_triples, int total_chars)
{
    __shared__ int hist[SPB][HPAD];   // 33 KB: per-segment char histogram
    __shared__ float red[4];

    const int wib  = threadIdx.x >> 6;
    const int lane = threadIdx.x & 63;
    const int s0 = blockIdx.x * SPB;
    const int s1 = min(s0 + SPB, n_triples);

    // ---- zero histogram ----
    for (int i = threadIdx.x; i < SPB * HPAD; i += 256)
        ((int*)hist)[i] = 0;
    __syncthreads();

    // ---- block's char range (each wave computes redundantly) ----
    int c_begin = lower_bound64(seg_ids, 0, total_chars, s0, lane);
    int c_end   = lower_bound64(seg_ids, c_begin, total_chars, s1, lane);

    // ---- build histogram: one LDS atomic per char, fully parallel ----
    for (int c = c_begin + threadIdx.x; c < c_end; c += 256) {
        int sid = seg_ids[c];          // coalesced
        int cid = char_ids[c];         // coalesced
        atomicAdd(&hist[sid - s0][cid], 1);   // random banks ~conflict-light
    }
    __syncthreads();

    // ---- dense t = hist x emb ----
    // lane owns segment s0+lane; wave wib owns dims [16*wib, 16*wib+16)
    const int dbase = __builtin_amdgcn_readfirstlane(wib * 16); // force uniform
    const int s = s0 + lane;

    float t[16];
    #pragma unroll
    for (int j = 0; j < 16; ++j) t[j] = 0.f;

    for (int c = 0; c < CHARSET; c += 4) {
        int4 cnts = *(const int4*)&hist[lane][c];   // conflict-free b128
        #pragma unroll
        for (int cc = 0; cc < 4; ++cc) {
            float cf = (float)((&cnts.x)[cc]);
            const float* ep = &char_emb[(c + cc) * D + dbase]; // uniform -> s_load
            #pragma unroll
            for (int j = 0; j < 16; ++j)
                t[j] = fmaf(cf, ep[j], t[j]);       // v_fma(v, s, v)
        }
    }

    // ---- epilogue: dist slice for my segment/dims ----
    float part = 0.f;
    if (s < n_triples) {
        int hid = head_ids[s];          // coalesced across lanes
        int rid = rel_ids[s];
        const float* hp = &ent_emb[(size_t)hid * D + dbase];  // 64B/lane gather
        const float* rp = &rel_emb[rid * D + dbase];          // tiny, cached
        #pragma unroll
        for (int j = 0; j < 16; ++j)
            part += fabsf(hp[j] + rp[j] - t[j]);
        // max(dist+GAMMA,0) == dist+GAMMA (dist>=0); GAMMA added as N*GAMMA once
    }

    // ---- reduce: wave -> block -> one atomic ----
    #pragma unroll
    for (int off = 32; off > 0; off >>= 1)
        part += __shfl_down(part, off, 64);
    if (lane == 0) red[wib] = part;
    __syncthreads();
    if (threadIdx.x == 0)
        atomicAdd(out, red[0] + red[1] + red[2] + red[3]);
}

extern "C" void kernel_launch(void* const* d_in, const int* in_sizes, int n_in,
                              void* d_out, int out_size, void* d_ws, size_t ws_size,
                              hipStream_t stream) {
    const int*   char_ids = (const int*)  d_in[0];
    const int*   seg_ids  = (const int*)  d_in[1];
    const int*   head_ids = (const int*)  d_in[2];
    const int*   rel_ids  = (const int*)  d_in[3];
    const float* char_emb = (const float*)d_in[4];
    const float* rel_emb  = (const float*)d_in[5];
    const float* ent_emb  = (const float*)d_in[6];
    float* out = (float*)d_out;

    const int total_chars = in_sizes[0];
    const int n_triples   = in_sizes[2];

    const int blocks = (n_triples + SPB - 1) / SPB;   // 1563

    init_out<<<1, 64, 0, stream>>>(out, (float)n_triples * GAMMA);
    attr_loss_kernel<<<blocks, 256, 0, stream>>>(
        char_ids, seg_ids, head_ids, rel_ids,
        char_emb, rel_emb, ent_emb, out,
        n_triples, total_chars);
}

// Round 5
// 55.195 us; speedup vs baseline: 6.5565x; 1.0969x over previous
//
#include <hip/hip_runtime.h>

#define D 64
#define CHARSET 128
#define GAMMA 1.0f
#define SPB 64          // segments per block
#define HPAD 132        // padded hist row (ints): 16B-aligned, 4-bank rotation/row

typedef short s8v  __attribute__((ext_vector_type(8)));   // bf16x8 frag (4 VGPRs)
typedef float f16v __attribute__((ext_vector_type(16)));  // fp32x16 accum

__device__ __forceinline__ short f32_to_bf16(float f) {
    unsigned u = __builtin_bit_cast(unsigned, f);
    unsigned r = (u + 0x7FFFu + ((u >> 16) & 1u)) >> 16;   // RNE
    return (short)r;
}

// preproc: start[g] = first char index whose segment >= 64*g; also init out
__global__ void preproc(const int* __restrict__ seg, int total, int nblocks,
                        int* __restrict__ start, float* __restrict__ out, float outv) {
    int c = blockIdx.x * blockDim.x + threadIdx.x;
    if (c == 0) out[0] = outv;
    if (c >= total) return;
    int scur  = seg[c];
    int sprev = (c == 0) ? -1 : seg[c - 1];
    for (int g = (sprev >> 6) + 1; (g << 6) <= scur; ++g) start[g] = c;   // sprev=-1 -> g=0
    if (c == total - 1)
        for (int g = (scur >> 6) + 1; g <= nblocks; ++g) start[g] = total;
}

__global__ void init_out(float* out, float v) {
    if (threadIdx.x == 0 && blockIdx.x == 0) out[0] = v;
}

// cooperative lower_bound (fallback path only)
__device__ __forceinline__ int lower_bound64(const int* __restrict__ seg,
                                             int lo, int hi, int target, int lane) {
    while (hi - lo > 64) {
        int step = (hi - lo) >> 6;
        int idx = lo + lane * step;
        int v = seg[idx];
        unsigned long long mask = __ballot(v < target);
        if (mask == 0ull) { hi = lo; break; }
        int k = 63 - __clzll(mask);
        int nhi = (k == 63) ? hi : (lo + (k + 1) * step);
        lo = lo + k * step; hi = nhi;
    }
    if (hi > lo) {
        int idx = lo + lane;
        int v = (idx < hi) ? seg[idx] : 0x7FFFFFFF;
        lo += __popcll(__ballot(v < target));
    }
    return lo;
}

template<bool USE_STARTS>
__global__ __launch_bounds__(256) void attr_mfma_kernel(
    const int* __restrict__ char_ids,
    const int* __restrict__ seg_ids,
    const int* __restrict__ head_ids,
    const int* __restrict__ rel_ids,
    const float* __restrict__ char_emb,
    const float* __restrict__ rel_emb,
    const float* __restrict__ ent_emb,
    const int* __restrict__ start,
    float* __restrict__ out,
    int n_triples, int total_chars)
{
    __shared__ int hist[SPB][HPAD];   // 33.8 KB
    __shared__ float red[4];

    const int wib  = threadIdx.x >> 6;
    const int lane = threadIdx.x & 63;
    const int s0   = blockIdx.x * SPB;

    // zero histogram
    for (int i = threadIdx.x; i < SPB * HPAD; i += 256) ((int*)hist)[i] = 0;

    // ---- B fragments: emb[k][dim] -> registers, loaded ONCE per wave ----
    // wave wib computes C tile (rb, cb): rows 32*rb.., cols 32*cb..
    const int cb = wib & 1, rb = wib >> 1;
    const int col = lane & 31, half = lane >> 5;
    s8v bfrag[8];
    #pragma unroll
    for (int st = 0; st < 8; ++st) {
        #pragma unroll
        for (int e = 0; e < 8; ++e) {
            int k = st * 16 + half * 8 + e;                 // B: col=lane&31, k=(lane>>5)*8+e
            bfrag[st][e] = f32_to_bf16(char_emb[k * D + cb * 32 + col]);  // 128B-coalesced/half
        }
    }
    __syncthreads();   // hist zeroed

    // ---- block's char range ----
    int c_begin, c_end;
    if (USE_STARTS) {
        c_begin = start[blockIdx.x];
        c_end   = start[blockIdx.x + 1];
    } else {
        c_begin = lower_bound64(seg_ids, 0, total_chars, s0, lane);
        c_end   = lower_bound64(seg_ids, c_begin, total_chars,
                                min(s0 + SPB, n_triples), lane);
    }

    // ---- histogram: one LDS atomic per char ----
    for (int c = c_begin + threadIdx.x; c < c_end; c += 256) {
        int sid = seg_ids[c];                       // coalesced
        int cid = char_ids[c];                      // coalesced
        atomicAdd(&hist[sid - s0][cid], 1);         // scattered banks
    }
    __syncthreads();

    // ---- t tile via MFMA: C[64 seg][64 dim] = hist · emb ----
    f16v acc = (f16v)0.f;
    const int arow = rb * 32 + col;                 // A: row=lane&31, k=(lane>>5)*8+e
    #pragma unroll
    for (int st = 0; st < 8; ++st) {
        int kbase = st * 16 + half * 8;
        int4 c0 = *(const int4*)&hist[arow][kbase];       // 16B-aligned (HPAD%4==0)
        int4 c1 = *(const int4*)&hist[arow][kbase + 4];
        s8v afrag;
        afrag[0] = f32_to_bf16((float)c0.x);  afrag[1] = f32_to_bf16((float)c0.y);
        afrag[2] = f32_to_bf16((float)c0.z);  afrag[3] = f32_to_bf16((float)c0.w);
        afrag[4] = f32_to_bf16((float)c1.x);  afrag[5] = f32_to_bf16((float)c1.y);
        afrag[6] = f32_to_bf16((float)c1.z);  afrag[7] = f32_to_bf16((float)c1.w);
        acc = __builtin_amdgcn_mfma_f32_32x32x16_bf16(afrag, bfrag[st], acc, 0, 0, 0);
    }

    // ---- epilogue: part += |h + r - t| over my 16 C elements ----
    // C layout (m74/m101): col=lane&31, row=(reg&3)+8*(reg>>2)+4*(lane>>5)
    float part = 0.f;
    const int dim = cb * 32 + col;
    #pragma unroll
    for (int reg = 0; reg < 16; ++reg) {
        int srow = (reg & 3) + 8 * (reg >> 2) + 4 * half;
        int s = s0 + rb * 32 + srow;
        if (s < n_triples) {
            int hid = head_ids[s];                          // broadcast per half-wave
            int rid = rel_ids[s];
            float h = ent_emb[(size_t)hid * D + dim];       // 128B contiguous per half
            float r = rel_emb[rid * D + dim];
            part += fabsf(h + r - acc[reg]);
            // max(dist+GAMMA,0)==dist+GAMMA; GAMMA added once as N*GAMMA in preproc
        }
    }

    // ---- reduce: wave -> block -> one atomic ----
    #pragma unroll
    for (int off = 32; off > 0; off >>= 1)
        part += __shfl_down(part, off, 64);
    if (lane == 0) red[wib] = part;
    __syncthreads();
    if (threadIdx.x == 0)
        atomicAdd(out, red[0] + red[1] + red[2] + red[3]);
}

extern "C" void kernel_launch(void* const* d_in, const int* in_sizes, int n_in,
                              void* d_out, int out_size, void* d_ws, size_t ws_size,
                              hipStream_t stream) {
    const int*   char_ids = (const int*)  d_in[0];
    const int*   seg_ids  = (const int*)  d_in[1];
    const int*   head_ids = (const int*)  d_in[2];
    const int*   rel_ids  = (const int*)  d_in[3];
    const float* char_emb = (const float*)d_in[4];
    const float* rel_emb  = (const float*)d_in[5];
    const float* ent_emb  = (const float*)d_in[6];
    float* out = (float*)d_out;

    const int total_chars = in_sizes[0];
    const int n_triples   = in_sizes[2];
    const int nblocks = (n_triples + SPB - 1) / SPB;
    const float outv = (float)n_triples * GAMMA;

    int* start = (int*)d_ws;
    if (ws_size >= (size_t)(nblocks + 1) * sizeof(int)) {
        preproc<<<(total_chars + 255) / 256, 256, 0, stream>>>(
            seg_ids, total_chars, nblocks, start, out, outv);
        attr_mfma_kernel<true><<<nblocks, 256, 0, stream>>>(
            char_ids, seg_ids, head_ids, rel_ids,
            char_emb, rel_emb, ent_emb, start, out, n_triples, total_chars);
    } else {
        init_out<<<1, 64, 0, stream>>>(out, outv);
        attr_mfma_kernel<false><<<nblocks, 256, 0, stream>>>(
            char_ids, seg_ids, head_ids, rel_ids,
            char_emb, rel_emb, ent_emb, start, out, n_triples, total_chars);
    }
}